// Round 7
// baseline (319.267 us; speedup 1.0000x reference)
//
#include <hip/hip_runtime.h>

// LevelLayer fused single kernel, manual grid barriers, R7: two-level
// low-contention barrier (16 leaf counters -> root -> 16 distributed release
// flags, 128-B line spacing, s_sleep backoff). R6's single-counter barrier
// caused a 512-spinner cacheline storm (VALUBusy 9.7%, time 188us).
// 512 blocks x 256 threads, 16 nodes/block, ~50 KB LDS -> all co-resident.
// space_emb FFN -> kNN(k=15, per-event) -> 2x GIN(residual) -> out FFN
// N=8192 nodes = 32 events x 256. Block i owns nodes [16i, 16i+16).
// 2 device-wide barriers: after space (pos/hA), after gin1 (hB). knn block i
// produces exactly gin block i's nbr rows; gin2 out range == out phase in range.
// Input dtype runtime-detected (bf16 vs fp32); outputs stored per same flag.
// d_out: h[8192*64] | x_emb[8192*4] | ei[2*122880].

#define N_NODES 8192
#define NPE     256
#define KNN     15
#define LAT     64
#define HID     128
#define NK      (N_NODES*KNN)
#define NBLK    512
#define NPB     16       // nodes per block
#define MST     20       // padded stride for m[64][MST], t[128][MST]
#define NLEAF   16
#define BPL     (NBLK/NLEAF)   // blocks per leaf = 32

typedef unsigned short bf16;
typedef unsigned int   u32;
typedef unsigned long long u64;

__device__ __forceinline__ float bf2f(bf16 s) {
    union { u32 u; float f; } v; v.u = ((u32)s) << 16; return v.f;
}
__device__ __forceinline__ bf16 f2bf(float f) {
    union { float f; u32 u; } v; v.f = f;
    u32 u = v.u + 0x7fffu + ((v.u >> 16) & 1u);   // RNE
    return (bf16)(u >> 16);
}

struct Params {
    const void *x, *se1, *bse1, *se2, *bse2,
               *g1a, *bg1a, *g1b, *bg1b, *g2a, *bg2a, *g2b, *bg2b,
               *oe1, *boe1, *oe2, *boe2;
    float *hA, *hB, *pos; int* nbr; int* bar; void* out;
};

union __align__(16) SMem {
    struct { float xv[NPB*4]; float W1[4*LAT]; float W2[LAT*LAT];
             float b1[LAT]; float b2[LAT]; float hid[NPB][LAT+1]; } sp;   // ~22 KB
    struct { float pos[NPE*3]; } kn;                                      // 3 KB
    struct { float W[LAT*HID]; float m[LAT*MST]; float t[HID*MST];
             float ba[HID]; float bb[LAT]; int nb[NPB*KNN]; } gi;         // ~49.6 KB
    struct { float W1[LAT*LAT]; float W2[LAT*4]; float b1[LAT];
             float b2[4]; float h[NPB][LAT+1]; float t[NPB][LAT+1]; } ou; // ~26 KB
};

// Two-level grid barrier. Region layout (int index, 32 ints = 128 B/line):
//   [0]           root counter
//   [32*(1+i)]    leaf counter i   (i < 16)
//   [32*(17+i)]   release flag i   (i < 16)
// Zeroed by captured hipMemsetAsync before each launch. Spin caps convert a
// co-residency failure into a wrong answer instead of a harness hang.
__device__ __forceinline__ void grid_barrier(int* bar) {
    __syncthreads();
    if (threadIdx.x == 0) {
        const int leaf = blockIdx.x & (NLEAF - 1);
        int* lc  = bar + 32 * (1 + leaf);
        int* rel = bar + 32 * (17 + leaf);
        __threadfence();
        const int lold = __hip_atomic_fetch_add(lc, 1, __ATOMIC_ACQ_REL, __HIP_MEMORY_SCOPE_AGENT);
        bool released = false;
        if (lold == BPL - 1) {                      // last arriver in this leaf
            const int rold = __hip_atomic_fetch_add(bar, 1, __ATOMIC_ACQ_REL, __HIP_MEMORY_SCOPE_AGENT);
            if (rold == NLEAF - 1) {                // last leaf -> release all
                #pragma unroll
                for (int i = 0; i < NLEAF; i++)
                    __hip_atomic_store(bar + 32 * (17 + i), 1, __ATOMIC_RELEASE, __HIP_MEMORY_SCOPE_AGENT);
                released = true;
            }
        }
        if (!released) {
            for (long t = 0; t < 100000000L; t++) {
                if (__hip_atomic_load(rel, __ATOMIC_ACQUIRE, __HIP_MEMORY_SCOPE_AGENT))
                    break;
                __builtin_amdgcn_s_sleep(4);        // ~256 cyc backoff
            }
        }
    }
    __syncthreads();
}

// stage n floats (n % 4 == 0) into LDS; vectorized both paths.
__device__ __forceinline__ void stage_w(float* dst, const void* src, int n, bool f32, int tid) {
    if (f32) {
        const float4* s = (const float4*)src; float4* d = (float4*)dst;
        for (int i = tid; i < n / 4; i += 256) d[i] = s[i];
    } else {
        const uint2* s = (const uint2*)src; float4* d = (float4*)dst;
        for (int i = tid; i < n / 4; i += 256) {
            const uint2 v = s[i]; float4 o;
            o.x = bf2f((bf16)(v.x & 0xffffu)); o.y = bf2f((bf16)(v.x >> 16));
            o.z = bf2f((bf16)(v.y & 0xffffu)); o.w = bf2f((bf16)(v.y >> 16));
            d[i] = o;
        }
    }
}

// GIN layer for 16 nodes: hout = hin + mlp(hin + sum_nbr hin)
__device__ __forceinline__ void gin_block(SMem& s, const float* __restrict__ hin,
    float* __restrict__ hout, const int* __restrict__ nbr,
    const void* Wa, const void* ba, const void* Wb, const void* bb,
    bool f32, int blk, int tid)
{
    const int base = blk * NPB;
    if (tid < NPB * KNN) s.gi.nb[tid] = nbr[base * KNN + tid] & (N_NODES - 1);
    stage_w(s.gi.W,  Wa, LAT * HID, f32, tid);
    stage_w(s.gi.ba, ba, HID,       f32, tid);
    stage_w(s.gi.bb, bb, LAT,       f32, tid);
    __syncthreads();
    // phase 1: m[f][n] = own + sum of 15 nbrs; thread = (node n, f-quad fq)
    {
        const int n = tid >> 4, fq = (tid & 15) * 4, gi0 = (base + n) * LAT + fq;
        float4 acc = *(const float4*)&hin[gi0];
        #pragma unroll
        for (int k = 0; k < KNN; k++) {
            const float4 v = *(const float4*)&hin[s.gi.nb[n * KNN + k] * LAT + fq];
            acc.x += v.x; acc.y += v.y; acc.z += v.z; acc.w += v.w;
        }
        s.gi.m[(fq + 0) * MST + n] = acc.x;
        s.gi.m[(fq + 1) * MST + n] = acc.y;
        s.gi.m[(fq + 2) * MST + n] = acc.z;
        s.gi.m[(fq + 3) * MST + n] = acc.w;
    }
    __syncthreads();
    // phase 2: t = relu(m @ Wa + ba); thread = (4 nodes x 2 u); Wa in LDS [f][u]
    {
        const int n0 = (tid >> 6) * 4, u0 = (tid & 63) * 2;
        float a00 = s.gi.ba[u0], a01 = s.gi.ba[u0 + 1];
        float a10 = a00, a11 = a01, a20 = a00, a21 = a01, a30 = a00, a31 = a01;
        for (int f = 0; f < LAT; f++) {
            const float4 mv = *(const float4*)&s.gi.m[f * MST + n0];
            const float2 wv = *(const float2*)&s.gi.W[f * HID + u0];
            a00 = fmaf(mv.x, wv.x, a00); a01 = fmaf(mv.x, wv.y, a01);
            a10 = fmaf(mv.y, wv.x, a10); a11 = fmaf(mv.y, wv.y, a11);
            a20 = fmaf(mv.z, wv.x, a20); a21 = fmaf(mv.z, wv.y, a21);
            a30 = fmaf(mv.w, wv.x, a30); a31 = fmaf(mv.w, wv.y, a31);
        }
        float* t0 = &s.gi.t[u0 * MST + n0];
        t0[0] = a00 > 0.f ? a00 : 0.f; t0[1] = a10 > 0.f ? a10 : 0.f;
        t0[2] = a20 > 0.f ? a20 : 0.f; t0[3] = a30 > 0.f ? a30 : 0.f;
        float* t1 = t0 + MST;
        t1[0] = a01 > 0.f ? a01 : 0.f; t1[1] = a11 > 0.f ? a11 : 0.f;
        t1[2] = a21 > 0.f ? a21 : 0.f; t1[3] = a31 > 0.f ? a31 : 0.f;
    }
    __syncthreads();
    stage_w(s.gi.W, Wb, HID * LAT, f32, tid);   // re-stage slab with Wb [u][f]
    __syncthreads();
    // phase 3: g = t @ Wb + bb; hout = own + g; thread = (4 nodes x 1 f)
    {
        const int n0 = (tid >> 6) * 4, f = tid & 63;
        float a0 = s.gi.bb[f], a1 = a0, a2 = a0, a3 = a0;
        for (int u = 0; u < HID; u++) {
            const float4 tv = *(const float4*)&s.gi.t[u * MST + n0];
            const float wv = s.gi.W[u * LAT + f];
            a0 = fmaf(tv.x, wv, a0); a1 = fmaf(tv.y, wv, a1);
            a2 = fmaf(tv.z, wv, a2); a3 = fmaf(tv.w, wv, a3);
        }
        const int g0 = (base + n0) * LAT + f;
        hout[g0]           = hin[g0]           + a0;
        hout[g0 + LAT]     = hin[g0 + LAT]     + a1;
        hout[g0 + 2 * LAT] = hin[g0 + 2 * LAT] + a2;
        hout[g0 + 3 * LAT] = hin[g0 + 3 * LAT] + a3;
    }
    __syncthreads();   // LDS reused next phase
}

__global__ __launch_bounds__(256) void k_fused(Params p)
{
    __shared__ SMem s;
    const int tid = threadIdx.x, blk = blockIdx.x;

    // ---- inline dtype detect (uniform scalar loads over 128 words) ----
    int cnt = 0;
    const u32* wdet = (const u32*)p.g1a;
    #pragma unroll 8
    for (int i = 0; i < 128; i++) {
        const u32 v = wdet[i];
        cnt += ((v >> 7)  & 0xffu) >= 0xC8u;
        cnt += ((v >> 23) & 0xffu) >= 0xC8u;
    }
    const bool f32 = cnt > 8;          // fp32 mantissa bits trip ~22%/half-word

    // ================= Phase A: space_emb for nodes [16*blk, +16) ==========
    {
        stage_w(s.sp.xv, f32 ? (const void*)((const float*)p.x + blk * NPB * 4)
                             : (const void*)((const bf16*)p.x + blk * NPB * 4),
                NPB * 4, f32, tid);
        stage_w(s.sp.W1, p.se1, 4 * LAT,   f32, tid);
        stage_w(s.sp.W2, p.se2, LAT * LAT, f32, tid);
        stage_w(s.sp.b1, p.bse1, LAT, f32, tid);
        stage_w(s.sp.b2, p.bse2, LAT, f32, tid);
        __syncthreads();
        const int ng = tid >> 6, f = tid & 63;
        #pragma unroll
        for (int g = 0; g < 4; g++) {
            const int nl = g * 4 + ng;
            float acc = s.sp.b1[f];
            #pragma unroll
            for (int i = 0; i < 4; i++)
                acc = fmaf(s.sp.xv[nl * 4 + i], s.sp.W1[i * LAT + f], acc);
            s.sp.hid[nl][f] = acc > 0.f ? acc : 0.01f * acc;   // leaky
        }
        __syncthreads();
        #pragma unroll
        for (int g = 0; g < 4; g++) {
            const int nl = g * 4 + ng, node = blk * NPB + nl;
            float a2 = s.sp.b2[f];
            for (int j = 0; j < LAT; j++)
                a2 = fmaf(s.sp.hid[nl][j], s.sp.W2[j * LAT + f], a2);
            p.hA[node * LAT + f] = a2;
            if (f < 3) p.pos[node * 3 + f] = a2;
        }
    }
    grid_barrier(p.bar);                         // pos + hA visible device-wide

    // ================= Phase B: kNN for nodes [16*blk, +16) ================
    {
        const int lb = (blk & 15) * NPB, eb = (blk >> 4) * NPE;
        for (int i = tid; i < NPE * 3; i += 256) s.kn.pos[i] = p.pos[eb * 3 + i];
        __syncthreads();
        const int wave = tid >> 6, lane = tid & 63;
        const int EI0 = N_NODES * LAT + N_NODES * 4;
        for (int r = 0; r < 4; r++) {
            const int nl = lb + wave * 4 + r;
            const int n  = eb + nl;
            const float px = s.kn.pos[nl*3], py = s.kn.pos[nl*3+1], pz = s.kn.pos[nl*3+2];
            u64 key[4];
            #pragma unroll
            for (int c = 0; c < 4; c++) {
                const int j = 64 * c + lane;
                const float dx = px - s.kn.pos[j*3], dy = py - s.kn.pos[j*3+1], dz = pz - s.kn.pos[j*3+2];
                float dd = __fmul_rn(dx, dx);                 // match np fp32 order
                dd = __fadd_rn(dd, __fmul_rn(dy, dy));
                dd = __fadd_rn(dd, __fmul_rn(dz, dz));
                key[c] = ((u64)__float_as_uint(dd) << 32) | (u32)j;
                if (j == nl) key[c] = ~0ull;                  // exclude self
            }
            u64 lmin = key[0] < key[1] ? key[0] : key[1];
            { u64 t = key[2] < key[3] ? key[2] : key[3]; lmin = t < lmin ? t : lmin; }
            int myj = 0;                                      // lane k holds k-th winner
            #pragma unroll
            for (int k = 0; k < KNN; k++) {
                u64 m = lmin;
                #pragma unroll
                for (int sft = 32; sft >= 1; sft >>= 1) {
                    const u64 o = __shfl_xor(m, sft, 64);
                    m = o < m ? o : m;
                }
                if (lane == k) myj = (int)(u32)m;
                #pragma unroll
                for (int c = 0; c < 4; c++) if (key[c] == m) key[c] = ~0ull;
                lmin = key[0] < key[1] ? key[0] : key[1];
                { u64 t = key[2] < key[3] ? key[2] : key[3]; lmin = t < lmin ? t : lmin; }
            }
            if (lane < KNN) {
                const int gj = eb + myj;
                p.nbr[n * KNN + lane] = gj;
                if (f32) {
                    float* o = (float*)p.out;
                    o[EI0 + n * KNN + lane]      = (float)gj;
                    o[EI0 + NK + n * KNN + lane] = (float)n;
                } else {
                    bf16* o = (bf16*)p.out;
                    o[EI0 + n * KNN + lane]      = f2bf((float)gj);
                    o[EI0 + NK + n * KNN + lane] = f2bf((float)n);
                }
            }
        }
        __syncthreads();   // this block's nbr rows done; LDS reused
    }

    // ================= Phase C: GIN1 hA -> hB ==============================
    gin_block(s, p.hA, p.hB, p.nbr, p.g1a, p.bg1a, p.g1b, p.bg1b, f32, blk, tid);
    grid_barrier(p.bar + 2048);                  // hB visible device-wide

    // ================= Phase D: GIN2 hB -> hA ==============================
    gin_block(s, p.hB, p.hA, p.nbr, p.g2a, p.bg2a, p.g2b, p.bg2b, f32, blk, tid);

    // ================= Phase E: out_emb + final stores =====================
    {
        stage_w(s.ou.W1, p.oe1, LAT * LAT, f32, tid);
        stage_w(s.ou.W2, p.oe2, LAT * 4,  f32, tid);
        stage_w(s.ou.b1, p.boe1, LAT, f32, tid);
        stage_w(s.ou.b2, p.boe2, 4,   f32, tid);
        __syncthreads();
        const int ng = tid >> 6, f = tid & 63;
        #pragma unroll
        for (int g = 0; g < 4; g++) {
            const int nl = g * 4 + ng, node = blk * NPB + nl;
            const float hv = p.hA[node * LAT + f];
            s.ou.h[nl][f] = hv;
            if (f32) ((float*)p.out)[node * LAT + f] = hv;          // output 0: h
            else     ((bf16*)p.out)[node * LAT + f] = f2bf(hv);
        }
        __syncthreads();
        #pragma unroll
        for (int g = 0; g < 4; g++) {
            const int nl = g * 4 + ng;
            float acc = s.ou.b1[f];
            for (int j = 0; j < LAT; j++)
                acc = fmaf(s.ou.h[nl][j], s.ou.W1[j * LAT + f], acc);
            s.ou.t[nl][f] = acc > 0.f ? acc : 0.01f * acc;          // leaky
        }
        __syncthreads();
        if (tid < NPB * 4) {
            const int nl = tid >> 2, fo = tid & 3, node = blk * NPB + nl;
            float a = s.ou.b2[fo];
            for (int j = 0; j < LAT; j++)
                a = fmaf(s.ou.t[nl][j], s.ou.W2[j * 4 + fo], a);
            const int xo = N_NODES * LAT + node * 4 + fo;           // output 1: x_emb
            if (f32) ((float*)p.out)[xo] = a;
            else     ((bf16*)p.out)[xo] = f2bf(a);
        }
    }
}

extern "C" void kernel_launch(void* const* d_in, const int* in_sizes, int n_in,
                              void* d_out, int out_size, void* d_ws, size_t ws_size,
                              hipStream_t stream)
{
    (void)in_sizes; (void)n_in; (void)out_size; (void)ws_size;
    char* ws = (char*)d_ws;
    Params p;
    p.x   = d_in[0];
    p.se1 = d_in[3];  p.bse1 = d_in[4];
    p.se2 = d_in[5];  p.bse2 = d_in[6];
    p.g1a = d_in[7];  p.bg1a = d_in[8];
    p.g1b = d_in[9];  p.bg1b = d_in[10];
    p.g2a = d_in[11]; p.bg2a = d_in[12];
    p.g2b = d_in[13]; p.bg2b = d_in[14];
    p.oe1 = d_in[15]; p.boe1 = d_in[16];
    p.oe2 = d_in[17]; p.boe2 = d_in[18];
    p.bar = (int*)ws;                                     // 2 barrier regions, 16 KB
    p.hA  = (float*)(ws + 16384);                         // 2 MB
    p.hB  = (float*)(ws + 16384 + 2097152);               // 2 MB
    p.pos = (float*)(ws + 16384 + 4194304);               // 96 KB
    p.nbr = (int*)(ws + 16384 + 4194304 + 131072);        // 480 KB
    p.out = d_out;

    hipMemsetAsync(ws, 0, 16384, stream);                 // zero barrier regions
    k_fused<<<NBLK, 256, 0, stream>>>(p);
}

// Round 8
// 182.944 us; speedup vs baseline: 1.7452x; 1.7452x over previous
//
#include <hip/hip_runtime.h>

// LevelLayer split pipeline v2 (R8). Lesson from R5-R7: software grid barriers
// on gfx950 cost 50-100x more than kernel-launch boundaries (each block's
// agent-scope fence/RMW emits L2 writeback/invalidate ops; time tracked the
// fenced-op count across R5/R6/R7). So: 4 plain kernels, HW does the flushes.
//   k_space    : space_emb FFN -> hA, pos
//   k_knn      : per-event kNN(k=15) -> nbr, ei(out)
//   k_gin1     : GIN layer 1 hA -> hB
//   k_gin2_out : GIN layer 2 (hB -> h in LDS) + out_emb -> d_out h, x_emb
// Dtype (bf16 vs fp32) detected inline per kernel from W_g1a bit patterns;
// weights staged to LDS with dtype branch. d_out: h[8192*64] | x_emb[8192*4]
// | ei[2*122880]. N=8192 = 32 events x 256. Block i owns nodes [16i,16i+16).

#define N_NODES 8192
#define NPE     256
#define KNN     15
#define LAT     64
#define HID     128
#define NK      (N_NODES*KNN)
#define NBLK    512
#define NPB     16       // nodes per block
#define MST     20       // padded stride for m[64][MST], t[128][MST]

typedef unsigned short bf16;
typedef unsigned int   u32;
typedef unsigned long long u64;

__device__ __forceinline__ float bf2f(bf16 s) {
    union { u32 u; float f; } v; v.u = ((u32)s) << 16; return v.f;
}
__device__ __forceinline__ bf16 f2bf(float f) {
    union { float f; u32 u; } v; v.f = f;
    u32 u = v.u + 0x7fffu + ((v.u >> 16) & 1u);   // RNE
    return (bf16)(u >> 16);
}

// inline dtype detect: uniform scalar scan of W_g1a's first 128 words.
// fp32 inputs: low-half mantissa bits read as bf16 exp >= 0xC8 ~22%/word.
// bf16 inputs: real exponents never reach 0xC8. Threshold 8 of ~28 expected.
__device__ __forceinline__ bool detect_f32(const void* g1a) {
    int cnt = 0;
    const u32* w = (const u32*)g1a;
    #pragma unroll 8
    for (int i = 0; i < 128; i++) {
        const u32 v = w[i];
        cnt += ((v >> 7)  & 0xffu) >= 0xC8u;
        cnt += ((v >> 23) & 0xffu) >= 0xC8u;
    }
    return cnt > 8;
}

// stage n floats (n % 4 == 0) into LDS; vectorized both dtype paths.
__device__ __forceinline__ void stage_w(float* dst, const void* src, int n, bool f32, int tid) {
    if (f32) {
        const float4* s = (const float4*)src; float4* d = (float4*)dst;
        for (int i = tid; i < n / 4; i += 256) d[i] = s[i];
    } else {
        const uint2* s = (const uint2*)src; float4* d = (float4*)dst;
        for (int i = tid; i < n / 4; i += 256) {
            const uint2 v = s[i]; float4 o;
            o.x = bf2f((bf16)(v.x & 0xffffu)); o.y = bf2f((bf16)(v.x >> 16));
            o.z = bf2f((bf16)(v.y & 0xffffu)); o.w = bf2f((bf16)(v.y >> 16));
            d[i] = o;
        }
    }
}

// ================= kernel 1: space_emb, 16 nodes/block =======================
__global__ __launch_bounds__(256) void k_space(
    const void* __restrict__ x, const void* __restrict__ g1a,
    const void* __restrict__ W1p, const void* __restrict__ b1p,
    const void* __restrict__ W2p, const void* __restrict__ b2p,
    float* __restrict__ hA, float* __restrict__ pos)
{
    __shared__ float sxv[NPB * 4];
    __shared__ float sW1[4 * LAT];
    __shared__ float sW2[LAT * LAT];
    __shared__ float sb1[LAT], sb2[LAT];
    __shared__ float shid[NPB][LAT + 1];
    const int tid = threadIdx.x, blk = blockIdx.x;
    const bool f32 = detect_f32(g1a);
    stage_w(sxv, f32 ? (const void*)((const float*)x + blk * NPB * 4)
                     : (const void*)((const bf16*)x + blk * NPB * 4), NPB * 4, f32, tid);
    stage_w(sW1, W1p, 4 * LAT,   f32, tid);
    stage_w(sW2, W2p, LAT * LAT, f32, tid);
    stage_w(sb1, b1p, LAT, f32, tid);
    stage_w(sb2, b2p, LAT, f32, tid);
    __syncthreads();
    const int ng = tid >> 6, f = tid & 63;
    #pragma unroll
    for (int g = 0; g < 4; g++) {
        const int nl = g * 4 + ng;
        float acc = sb1[f];
        #pragma unroll
        for (int i = 0; i < 4; i++)
            acc = fmaf(sxv[nl * 4 + i], sW1[i * LAT + f], acc);
        shid[nl][f] = acc > 0.f ? acc : 0.01f * acc;   // leaky
    }
    __syncthreads();
    #pragma unroll
    for (int g = 0; g < 4; g++) {
        const int nl = g * 4 + ng, node = blk * NPB + nl;
        float a2 = sb2[f];
        for (int j = 0; j < LAT; j++)
            a2 = fmaf(shid[nl][j], sW2[j * LAT + f], a2);
        hA[node * LAT + f] = a2;
        if (f < 3) pos[node * 3 + f] = a2;
    }
}

// ================= kernel 2: kNN, 16 nodes/block (wave = 4 nodes) ============
__global__ __launch_bounds__(256) void k_knn(
    const float* __restrict__ pos, const void* __restrict__ g1a,
    int* __restrict__ nbr, void* __restrict__ d_out)
{
    __shared__ float sp[NPE * 3];
    const int tid = threadIdx.x, blk = blockIdx.x;
    const bool f32 = detect_f32(g1a);
    const int lb = (blk & 15) * NPB, eb = (blk >> 4) * NPE;
    for (int i = tid; i < NPE * 3; i += 256) sp[i] = pos[eb * 3 + i];
    __syncthreads();
    const int wave = tid >> 6, lane = tid & 63;
    const int EI0 = N_NODES * LAT + N_NODES * 4;
    for (int r = 0; r < 4; r++) {
        const int nl = lb + wave * 4 + r;
        const int n  = eb + nl;
        const float px = sp[nl*3], py = sp[nl*3+1], pz = sp[nl*3+2];
        u64 key[4];
        #pragma unroll
        for (int c = 0; c < 4; c++) {
            const int j = 64 * c + lane;
            const float dx = px - sp[j*3], dy = py - sp[j*3+1], dz = pz - sp[j*3+2];
            float dd = __fmul_rn(dx, dx);                 // match np fp32 order
            dd = __fadd_rn(dd, __fmul_rn(dy, dy));
            dd = __fadd_rn(dd, __fmul_rn(dz, dz));
            key[c] = ((u64)__float_as_uint(dd) << 32) | (u32)j;
            if (j == nl) key[c] = ~0ull;                  // exclude self
        }
        u64 lmin = key[0] < key[1] ? key[0] : key[1];
        { u64 t = key[2] < key[3] ? key[2] : key[3]; lmin = t < lmin ? t : lmin; }
        int myj = 0;                                      // lane k holds k-th winner
        #pragma unroll
        for (int k = 0; k < KNN; k++) {
            u64 m = lmin;
            #pragma unroll
            for (int sft = 32; sft >= 1; sft >>= 1) {
                const u64 o = __shfl_xor(m, sft, 64);
                m = o < m ? o : m;
            }
            if (lane == k) myj = (int)(u32)m;
            #pragma unroll
            for (int c = 0; c < 4; c++) if (key[c] == m) key[c] = ~0ull;
            lmin = key[0] < key[1] ? key[0] : key[1];
            { u64 t = key[2] < key[3] ? key[2] : key[3]; lmin = t < lmin ? t : lmin; }
        }
        if (lane < KNN) {
            const int gj = eb + myj;
            nbr[n * KNN + lane] = gj;
            if (f32) {
                float* o = (float*)d_out;
                o[EI0 + n * KNN + lane]      = (float)gj;
                o[EI0 + NK + n * KNN + lane] = (float)n;
            } else {
                bf16* o = (bf16*)d_out;
                o[EI0 + n * KNN + lane]      = f2bf((float)gj);
                o[EI0 + NK + n * KNN + lane] = f2bf((float)n);
            }
        }
    }
}

// ================= GIN compute core (shared by kernels 3 & 4) ================
// If sh != nullptr, phase-3 result goes to sh[n][65-stride] (for fused out_emb)
// instead of global hout.
struct GinLds {
    float W[LAT * HID];
    float m[LAT * MST];
    float t[HID * MST];
    float ba[HID], bb[LAT];
    int   nb[NPB * KNN];
};

__device__ __forceinline__ void gin_core(GinLds& s, const float* __restrict__ hin,
    float* __restrict__ hout, float (* __restrict__ sh)[LAT + 1],
    const int* __restrict__ nbr,
    const void* Wa, const void* ba, const void* Wb, const void* bb,
    bool f32, int blk, int tid)
{
    const int base = blk * NPB;
    if (tid < NPB * KNN) s.nb[tid] = nbr[base * KNN + tid] & (N_NODES - 1);
    stage_w(s.W,  Wa, LAT * HID, f32, tid);
    stage_w(s.ba, ba, HID,       f32, tid);
    stage_w(s.bb, bb, LAT,       f32, tid);
    __syncthreads();
    // phase 1: m[f][n] = own + sum of 15 nbrs; thread = (node n, f-quad fq)
    {
        const int n = tid >> 4, fq = (tid & 15) * 4, gi0 = (base + n) * LAT + fq;
        float4 acc = *(const float4*)&hin[gi0];
        #pragma unroll
        for (int k = 0; k < KNN; k++) {
            const float4 v = *(const float4*)&hin[s.nb[n * KNN + k] * LAT + fq];
            acc.x += v.x; acc.y += v.y; acc.z += v.z; acc.w += v.w;
        }
        s.m[(fq + 0) * MST + n] = acc.x;
        s.m[(fq + 1) * MST + n] = acc.y;
        s.m[(fq + 2) * MST + n] = acc.z;
        s.m[(fq + 3) * MST + n] = acc.w;
    }
    __syncthreads();
    // phase 2: t = relu(m @ Wa + ba); thread = (4 nodes x 2 u); Wa in LDS [f][u]
    {
        const int n0 = (tid >> 6) * 4, u0 = (tid & 63) * 2;
        float a00 = s.ba[u0], a01 = s.ba[u0 + 1];
        float a10 = a00, a11 = a01, a20 = a00, a21 = a01, a30 = a00, a31 = a01;
        for (int f = 0; f < LAT; f++) {
            const float4 mv = *(const float4*)&s.m[f * MST + n0];
            const float2 wv = *(const float2*)&s.W[f * HID + u0];
            a00 = fmaf(mv.x, wv.x, a00); a01 = fmaf(mv.x, wv.y, a01);
            a10 = fmaf(mv.y, wv.x, a10); a11 = fmaf(mv.y, wv.y, a11);
            a20 = fmaf(mv.z, wv.x, a20); a21 = fmaf(mv.z, wv.y, a21);
            a30 = fmaf(mv.w, wv.x, a30); a31 = fmaf(mv.w, wv.y, a31);
        }
        float* t0 = &s.t[u0 * MST + n0];
        t0[0] = a00 > 0.f ? a00 : 0.f; t0[1] = a10 > 0.f ? a10 : 0.f;
        t0[2] = a20 > 0.f ? a20 : 0.f; t0[3] = a30 > 0.f ? a30 : 0.f;
        float* t1 = t0 + MST;
        t1[0] = a01 > 0.f ? a01 : 0.f; t1[1] = a11 > 0.f ? a11 : 0.f;
        t1[2] = a21 > 0.f ? a21 : 0.f; t1[3] = a31 > 0.f ? a31 : 0.f;
    }
    __syncthreads();
    stage_w(s.W, Wb, HID * LAT, f32, tid);   // re-stage slab with Wb [u][f]
    __syncthreads();
    // phase 3: g = t @ Wb + bb; h = own + g -> global hout OR LDS sh
    {
        const int n0 = (tid >> 6) * 4, f = tid & 63;
        float a0 = s.bb[f], a1 = a0, a2 = a0, a3 = a0;
        for (int u = 0; u < HID; u++) {
            const float4 tv = *(const float4*)&s.t[u * MST + n0];
            const float wv = s.W[u * LAT + f];
            a0 = fmaf(tv.x, wv, a0); a1 = fmaf(tv.y, wv, a1);
            a2 = fmaf(tv.z, wv, a2); a3 = fmaf(tv.w, wv, a3);
        }
        const int g0 = (base + n0) * LAT + f;
        const float h0 = hin[g0]           + a0;
        const float h1 = hin[g0 + LAT]     + a1;
        const float h2 = hin[g0 + 2*LAT]   + a2;
        const float h3 = hin[g0 + 3*LAT]   + a3;
        if (sh) {
            sh[n0][f] = h0; sh[n0+1][f] = h1; sh[n0+2][f] = h2; sh[n0+3][f] = h3;
        } else {
            hout[g0] = h0; hout[g0+LAT] = h1; hout[g0+2*LAT] = h2; hout[g0+3*LAT] = h3;
        }
    }
    __syncthreads();
}

// ================= kernel 3: GIN1 hA -> hB ==================================
__global__ __launch_bounds__(256) void k_gin1(
    const float* __restrict__ hA, float* __restrict__ hB,
    const int* __restrict__ nbr, const void* __restrict__ g1a,
    const void* __restrict__ ba, const void* __restrict__ Wb, const void* __restrict__ bb)
{
    __shared__ GinLds s;
    const int tid = threadIdx.x, blk = blockIdx.x;
    const bool f32 = detect_f32(g1a);
    gin_core(s, hA, hB, nullptr, nbr, g1a, ba, Wb, bb, f32, blk, tid);
}

// ================= kernel 4: GIN2 (hB -> h in LDS) + out_emb =================
__global__ __launch_bounds__(256) void k_gin2_out(
    const float* __restrict__ hB, const int* __restrict__ nbr,
    const void* __restrict__ g1a,
    const void* __restrict__ Wa, const void* __restrict__ ba,
    const void* __restrict__ Wb, const void* __restrict__ bb,
    const void* __restrict__ W1p, const void* __restrict__ b1p,
    const void* __restrict__ W2p, const void* __restrict__ b2p,
    void* __restrict__ d_out)
{
    __shared__ float sh[NPB][LAT + 1];        // survives the union reuse below
    __shared__ union {
        GinLds gi;
        struct { float W1[LAT * LAT]; float W2[LAT * 4];
                 float b1[LAT]; float b2[4]; float t[NPB][LAT + 1]; } ou;
    } s;
    const int tid = threadIdx.x, blk = blockIdx.x;
    const bool f32 = detect_f32(g1a);
    gin_core(s.gi, hB, nullptr, sh, nbr, Wa, ba, Wb, bb, f32, blk, tid);
    // ---- out_emb on the 16 nodes now sitting in sh ----
    stage_w(s.ou.W1, W1p, LAT * LAT, f32, tid);
    stage_w(s.ou.W2, W2p, LAT * 4,  f32, tid);
    stage_w(s.ou.b1, b1p, LAT, f32, tid);
    stage_w(s.ou.b2, b2p, 4,   f32, tid);
    __syncthreads();
    const int ng = tid >> 6, f = tid & 63;
    #pragma unroll
    for (int g = 0; g < 4; g++) {
        const int nl = g * 4 + ng, node = blk * NPB + nl;
        const float hv = sh[nl][f];
        if (f32) ((float*)d_out)[node * LAT + f] = hv;          // output 0: h
        else     ((bf16*)d_out)[node * LAT + f] = f2bf(hv);
    }
    #pragma unroll
    for (int g = 0; g < 4; g++) {
        const int nl = g * 4 + ng;
        float acc = s.ou.b1[f];
        for (int j = 0; j < LAT; j++)
            acc = fmaf(sh[nl][j], s.ou.W1[j * LAT + f], acc);
        s.ou.t[nl][f] = acc > 0.f ? acc : 0.01f * acc;          // leaky
    }
    __syncthreads();
    if (tid < NPB * 4) {
        const int nl = tid >> 2, fo = tid & 3, node = blk * NPB + nl;
        float a = s.ou.b2[fo];
        for (int j = 0; j < LAT; j++)
            a = fmaf(s.ou.t[nl][j], s.ou.W2[j * 4 + fo], a);
        const int xo = N_NODES * LAT + node * 4 + fo;           // output 1: x_emb
        if (f32) ((float*)d_out)[xo] = a;
        else     ((bf16*)d_out)[xo] = f2bf(a);
    }
}

extern "C" void kernel_launch(void* const* d_in, const int* in_sizes, int n_in,
                              void* d_out, int out_size, void* d_ws, size_t ws_size,
                              hipStream_t stream)
{
    (void)in_sizes; (void)n_in; (void)out_size; (void)ws_size;
    char* ws = (char*)d_ws;
    float* hA  = (float*)ws;                              // 2 MB
    float* hB  = (float*)(ws + 2097152);                  // 2 MB
    float* pos = (float*)(ws + 4194304);                  // 96 KB
    int*   nbr = (int*)(ws + 4194304 + 131072);           // 480 KB

    const void* x    = d_in[0];
    const void* se1  = d_in[3],  *bse1 = d_in[4];
    const void* se2  = d_in[5],  *bse2 = d_in[6];
    const void* g1a  = d_in[7],  *bg1a = d_in[8];
    const void* g1b  = d_in[9],  *bg1b = d_in[10];
    const void* g2a  = d_in[11], *bg2a = d_in[12];
    const void* g2b  = d_in[13], *bg2b = d_in[14];
    const void* oe1  = d_in[15], *boe1 = d_in[16];
    const void* oe2  = d_in[17], *boe2 = d_in[18];

    k_space   <<<NBLK, 256, 0, stream>>>(x, g1a, se1, bse1, se2, bse2, hA, pos);
    k_knn     <<<NBLK, 256, 0, stream>>>(pos, g1a, nbr, d_out);
    k_gin1    <<<NBLK, 256, 0, stream>>>(hA, hB, nbr, g1a, bg1a, g1b, bg1b);
    k_gin2_out<<<NBLK, 256, 0, stream>>>(hB, nbr, g1a, g2a, bg2a, g2b, bg2b,
                                         oe1, boe1, oe2, boe2, d_out);
}